// Round 24
// baseline (219.399 us; speedup 1.0000x reference)
//
#include <hip/hip_runtime.h>

#define NROI  2048
#define CCH   256
#define IMH   200
#define IMW   200
#define CROP  7
#define PP    49
#define FANIN 12544
#define HID   1024

typedef _Float16 f16x8 __attribute__((ext_vector_type(8)));
typedef _Float16 f16x4 __attribute__((ext_vector_type(4)));
typedef __attribute__((ext_vector_type(4))) float f32x4;

__device__ __forceinline__ void gload16(const void* g, void* l) {
    __builtin_amdgcn_global_load_lds(
        (const __attribute__((address_space(1))) void*)g,
        (__attribute__((address_space(3))) void*)l, 16, 0, 0);
}

// ---------------------------------------------------------------------------
// Pass A: [0,2048) convert x -> x16 (f16, same c-major layout, grid-stride,
// sequential across blocks -> proven ~5.5 TB/s); [2048,3072) permute w1;
// [3072,3136) convert w2.
// ---------------------------------------------------------------------------
__global__ __launch_bounds__(256) void prep_convert(
    const float* __restrict__ x, _Float16* __restrict__ x16,
    const float* __restrict__ w1, _Float16* __restrict__ w1P,
    const float* __restrict__ w2, _Float16* __restrict__ w2F)
{
    __shared__ _Float16 row[FANIN];    // used by permute arm only (25 KB)
    const int bid = blockIdx.x;
    const int tid = threadIdx.x;

    if (bid < 2048) {
        const int n4 = 4 * CCH * IMH * IMW / 4;   // 10,240,000 float4
        for (int g = bid * 256 + tid; g < n4; g += 2048 * 256) {
            const float4 v = ((const float4*)x)[g];
            f16x4 o = {(_Float16)v.x, (_Float16)v.y, (_Float16)v.z, (_Float16)v.w};
            ((f16x4*)x16)[g] = o;
        }
    } else if (bid < 3072) {
        const int o = bid - 2048;
        const float* src = w1 + (size_t)o * FANIN;
        for (int g = tid; g < FANIN / 4; g += 256) {
            const float4 v = *(const float4*)(src + g * 4);
            f16x4 f = {(_Float16)v.x, (_Float16)v.y, (_Float16)v.z, (_Float16)v.w};
            *(f16x4*)&row[g * 4] = f;
        }
        __syncthreads();
        _Float16* dst = w1P + (size_t)o * FANIN;
        for (int g = tid; g < FANIN; g += 256) {
            const int p = g >> 8;          // 0..48
            const int c = g & 255;
            dst[g] = row[c * PP + p];
        }
    } else {
        const int cb = bid - 3072;         // 0..63
        for (int g = cb * 256 + tid; g < HID * HID / 4; g += 64 * 256) {
            const float4 v = ((const float4*)w2)[g];
            f16x4 o = {(_Float16)v.x, (_Float16)v.y, (_Float16)v.z, (_Float16)v.w};
            ((f16x4*)w2F)[g] = o;
        }
    }
}

// ---------------------------------------------------------------------------
// Pass B: transpose x16[b][c][h][w] -> xT[b][h][w][c]. Block = (half,h,b).
// Reads hit L3-resident x16 (82 MB). LDS [256][106] f16: write-phase column
// reads are 2-way max (bank = 8*(tid&7)+(tid>>4)+21k, stride 53 dwords).
// ---------------------------------------------------------------------------
__global__ __launch_bounds__(256) void transpose16(
    const _Float16* __restrict__ x16, _Float16* __restrict__ xT)
{
    __shared__ _Float16 t[256][106];   // 54,272 B -> 2 blocks/CU

    const int half = blockIdx.x;       // 0,1
    const int h    = blockIdx.y;       // 0..199
    const int b    = blockIdx.z;       // 0..3
    const int tid  = threadIdx.x;
    const int cg  = tid >> 4;          // 0..15 (channel group within pass)
    const int l16 = tid & 15;          // 0..15

    const _Float16* srcb = x16 + ((size_t)(b * CCH) * IMH + h) * IMW + half * 100;
    // stage: 16 passes; group reads channel c's 100 f16 (13 lanes x f16x8,
    // lane 12 overruns 4 f16 into adjacent valid memory -- benign)
#pragma unroll
    for (int p = 0; p < 16; ++p) {
        const int c = p * 16 + cg;
        if (l16 <= 12) {
            f16x8 v = *(const f16x8*)(srcb + (size_t)c * (IMH * IMW) + l16 * 8);
            *(f16x8*)&t[c][l16 * 8] = v;
        }
    }
    __syncthreads();

    // write: unit u = (w = u>>3, sg = u&7); 8 column reads (2-way banks),
    // 128-B contiguous store runs per 8 lanes
    _Float16* dst0 = xT + ((size_t)(b * IMH + h) * IMW + half * 100) * CCH;
    for (int u = tid; u < 3200; u += 256) {
        const int w  = u >> 5;          // 0..99
        const int sg = u & 31;          // 0..31  -> c = sg*8..sg*8+7
        f16x8 o;
#pragma unroll
        for (int k = 0; k < 8; ++k) o[k] = t[sg * 8 + k][w];
        *(f16x8*)(dst0 + (size_t)w * CCH + sg * 8) = o;
    }
}

// ---------------------------------------------------------------------------
// RoIAlign gather: block = ROI n, 4 waves; wave = one sample across channels.
// Crops K-order: k' = p*256 + c  (w1 permuted identically).
// ---------------------------------------------------------------------------
__global__ __launch_bounds__(256) void roi_gather_kernel(
    const _Float16* __restrict__ xT, const float* __restrict__ rois,
    _Float16* __restrict__ crops)
{
    const int n    = blockIdx.x;
    const int wave = threadIdx.x >> 6;
    const int lane = threadIdx.x & 63;

    const int   b   = (int)rois[(size_t)n * 5 + 0];
    const float rx1 = rois[(size_t)n * 5 + 1];
    const float ry1 = rois[(size_t)n * 5 + 2];
    const float rx2 = rois[(size_t)n * 5 + 3];
    const float ry2 = rois[(size_t)n * 5 + 4];
    const float bw = (rx2 - rx1) / 7.0f;
    const float bh = (ry2 - ry1) / 7.0f;

    const _Float16* xb = xT + (size_t)b * (IMH * IMW * CCH);
    _Float16* crow = crops + (size_t)n * FANIN;

    for (int p = wave; p < PP; p += 4) {
        const int i = p / 7;           // bin row -> y
        const int j = p - i * 7;       // bin col -> x
        float px = __fadd_rn(rx1, __fmul_rn((float)j + 0.5f, bw));
        float py = __fadd_rn(ry1, __fmul_rn((float)i + 0.5f, bh));
        px = fminf(fmaxf(px, 0.0f), (float)(IMW - 1));
        py = fminf(fmaxf(py, 0.0f), (float)(IMH - 1));
        const float fx = floorf(px), fy = floorf(py);
        const int x0 = (int)fx, y0 = (int)fy;
        const int dxo = (min(x0 + 1, IMW - 1) - x0) * CCH;
        const int dyo = (min(y0 + 1, IMH - 1) - y0) * (IMW * CCH);
        const float wx = px - fx, wy = py - fy;

        const _Float16* cb = xb + (size_t)(y0 * IMW + x0) * CCH + lane * 4;
        const f16x4 A = *(const f16x4*)(cb);
        const f16x4 B = *(const f16x4*)(cb + dxo);
        const f16x4 C = *(const f16x4*)(cb + dyo);
        const f16x4 D = *(const f16x4*)(cb + dyo + dxo);

        f16x4 o;
#pragma unroll
        for (int e = 0; e < 4; ++e) {
            const float v00 = (float)A[e], v01 = (float)B[e];
            const float v10 = (float)C[e], v11 = (float)D[e];
            const float top = v00 + wx * (v01 - v00);
            const float bot = v10 + wx * (v11 - v10);
            o[e] = (_Float16)(top + wy * (bot - top));
        }
        *(f16x4*)(crow + p * CCH + lane * 4) = o;
    }
}

// ---------------------------------------------------------------------------
// FC1 GEMM (NT), 256x256 tile, BK=64, 8 waves, double-buffered 2-phase,
// XCD-pinned flat grid (224 blocks). P partials stored as f16.
// ---------------------------------------------------------------------------
__global__ __launch_bounds__(512, 1) void gemm_f16_256(
    const _Float16* __restrict__ A, const _Float16* __restrict__ B,
    _Float16* __restrict__ P, int M, int N, int K, int kLen)
{
    __shared__ _Float16 lds[2][2][256][64];   // [buf][op][row][slot] 128 KB

    const int flat = blockIdx.x;
    const int xcd  = flat & 7;
    const int idx  = flat >> 3;          // 0..27
    const int bn4  = xcd & 3;            // n-tile 0..3
    const int half = xcd >> 2;           // 0..1
    const int bm8  = half * 4 + (idx & 3);   // m-tile 0..7
    const int z    = idx >> 2;           // 0..6

    const int tid  = threadIdx.x;
    const int wave = tid >> 6;           // 0..7
    const int lane = tid & 63;
    const int bm = bm8 * 256;
    const int bn = bn4 * 256;
    const int kBase = z * kLen;
    const int wr = wave >> 1;            // 0..3 (M)
    const int wc = wave & 1;             // 0..1 (N)

    f32x4 acc[4][8];
#pragma unroll
    for (int i = 0; i < 4; ++i)
#pragma unroll
        for (int j = 0; j < 8; ++j) acc[i][j] = (f32x4){0.f, 0.f, 0.f, 0.f};

    const int r_st = wave * 32 + (lane >> 3);
    const int s_st = ((lane & 7) ^ ((lane >> 4) & 3)) * 8;   // f16 units
    const _Float16* gA = A + (size_t)(bm + r_st) * K + kBase + s_st;
    const _Float16* gB = B + (size_t)(bn + r_st) * K + kBase + s_st;
    const size_t rstep8 = (size_t)8 * K;

    const int li = lane & 15;
    const int hi = lane >> 4;            // 0..3
    const int swb = (li >> 1) & 3;       // row-pair xor term

    // prologue: stage tile 0 into buf 0
    {
        _Float16* dA = &lds[0][0][wave * 32][0];
        _Float16* dB = &lds[0][1][wave * 32][0];
#pragma unroll
        for (int ck = 0; ck < 4; ++ck) {
            gload16(gA + ck * rstep8, dA + ck * 512);
            gload16(gB + ck * rstep8, dB + ck * 512);
        }
    }
    __syncthreads();

    int cur = 0;
    for (int kt = 0; kt < kLen; kt += 64) {
        if (kt + 64 < kLen) {
            _Float16* dA = &lds[cur ^ 1][0][wave * 32][0];
            _Float16* dB = &lds[cur ^ 1][1][wave * 32][0];
#pragma unroll
            for (int ck = 0; ck < 4; ++ck) {
                gload16(gA + kt + 64 + ck * rstep8, dA + ck * 512);
                gload16(gB + kt + 64 + ck * rstep8, dB + ck * 512);
            }
        }

#pragma unroll
        for (int kk = 0; kk < 2; ++kk) {
            const int sw = (((kk << 2) | hi) ^ swb) * 8;     // f16 offset
            f16x8 a[4], b[8];
#pragma unroll
            for (int m = 0; m < 4; ++m)
                a[m] = *(const f16x8*)&lds[cur][0][wr * 64 + m * 16 + li][sw];
#pragma unroll
            for (int n = 0; n < 8; ++n)
                b[n] = *(const f16x8*)&lds[cur][1][wc * 128 + n * 16 + li][sw];
#pragma unroll
            for (int m = 0; m < 4; ++m)
#pragma unroll
                for (int n = 0; n < 8; ++n)
                    acc[m][n] = __builtin_amdgcn_mfma_f32_16x16x32_f16(a[m], b[n], acc[m][n], 0, 0, 0);
        }
        __syncthreads();
        cur ^= 1;
    }

    _Float16* Pz = P + (size_t)z * M * N;
#pragma unroll
    for (int m = 0; m < 4; ++m)
#pragma unroll
        for (int n = 0; n < 8; ++n) {
            const int col = bn + wc * 128 + n * 16 + li;
#pragma unroll
            for (int e = 0; e < 4; ++e) {
                const int row = bm + wr * 64 + m * 16 + hi * 4 + e;
                Pz[(size_t)row * N + col] = (_Float16)acc[m][n][e];
            }
        }
}

// ---------------------------------------------------------------------------
// FC2 GEMM (NT), 128x128 tile, BK=64, double-buffered 2-phase, f16 partials.
// ---------------------------------------------------------------------------
__global__ __launch_bounds__(256, 2) void gemm_f16(
    const _Float16* __restrict__ A, const _Float16* __restrict__ B,
    _Float16* __restrict__ P, int M, int N, int K, int kLen)
{
    __shared__ _Float16 lds[2][2][128][64];   // 64 KB -> 2 blocks/CU

    const int tid  = threadIdx.x;
    const int wave = tid >> 6;
    const int lane = tid & 63;
    const int bm = blockIdx.y * 128;
    const int bn = blockIdx.x * 128;
    const int kBase = blockIdx.z * kLen;
    const int wr = wave >> 1, wc = wave & 1;

    f32x4 acc[4][4];
#pragma unroll
    for (int i = 0; i < 4; ++i)
#pragma unroll
        for (int j = 0; j < 4; ++j) acc[i][j] = (f32x4){0.f, 0.f, 0.f, 0.f};

    const int r_st = wave * 32 + (lane >> 3);
    const int s_st = ((lane & 7) ^ ((lane >> 4) & 3)) * 8;   // f16 units
    const _Float16* gA = A + (size_t)(bm + r_st) * K + kBase + s_st;
    const _Float16* gB = B + (size_t)(bn + r_st) * K + kBase + s_st;
    const size_t rstep8 = (size_t)8 * K;

    const int li = lane & 15;
    const int hi = lane >> 4;            // 0..3
    const int swb = (li >> 1) & 3;       // row-pair xor term

    {
        _Float16* dA = &lds[0][0][wave * 32][0];
        _Float16* dB = &lds[0][1][wave * 32][0];
#pragma unroll
        for (int ck = 0; ck < 4; ++ck) {
            gload16(gA + ck * rstep8, dA + ck * 512);
            gload16(gB + ck * rstep8, dB + ck * 512);
        }
    }
    __syncthreads();

    int cur = 0;
    for (int kt = 0; kt < kLen; kt += 64) {
        if (kt + 64 < kLen) {
            _Float16* dA = &lds[cur ^ 1][0][wave * 32][0];
            _Float16* dB = &lds[cur ^ 1][1][wave * 32][0];
#pragma unroll
            for (int ck = 0; ck < 4; ++ck) {
                gload16(gA + kt + 64 + ck * rstep8, dA + ck * 512);
                gload16(gB + kt + 64 + ck * rstep8, dB + ck * 512);
            }
        }

#pragma unroll
        for (int kk = 0; kk < 2; ++kk) {
            const int sw = (((kk << 2) | hi) ^ swb) * 8;     // f16 offset
            f16x8 a[4], b[4];
#pragma unroll
            for (int m = 0; m < 4; ++m)
                a[m] = *(const f16x8*)&lds[cur][0][wr * 64 + m * 16 + li][sw];
#pragma unroll
            for (int n = 0; n < 4; ++n)
                b[n] = *(const f16x8*)&lds[cur][1][wc * 64 + n * 16 + li][sw];
#pragma unroll
            for (int m = 0; m < 4; ++m)
#pragma unroll
                for (int n = 0; n < 4; ++n)
                    acc[m][n] = __builtin_amdgcn_mfma_f32_16x16x32_f16(a[m], b[n], acc[m][n], 0, 0, 0);
        }
        __syncthreads();
        cur ^= 1;
    }

    _Float16* Pz = P + (size_t)blockIdx.z * M * N;
#pragma unroll
    for (int m = 0; m < 4; ++m)
#pragma unroll
        for (int n = 0; n < 4; ++n) {
            const int col = bn + wc * 64 + n * 16 + li;
#pragma unroll
            for (int e = 0; e < 4; ++e) {
                const int row = bm + wr * 64 + m * 16 + hi * 4 + e;
                Pz[(size_t)row * N + col] = (_Float16)acc[m][n][e];
            }
        }
}

// ---------------------------------------------------------------------------
// relu(sum_z P[z] + bias) -> f16   (P slices are f16; accumulate in f32)
// ---------------------------------------------------------------------------
__global__ __launch_bounds__(256) void combine_relu_f16(
    const _Float16* __restrict__ P, int Z, const float* __restrict__ bias,
    _Float16* __restrict__ H)
{
    const int g = blockIdx.x * 256 + threadIdx.x;      // f16x8 group
    const size_t MN8 = (size_t)NROI * HID / 8;
    float s[8] = {0, 0, 0, 0, 0, 0, 0, 0};
    for (int z = 0; z < Z; ++z) {
        const f16x8 p = ((const f16x8*)P)[z * MN8 + g];
#pragma unroll
        for (int e = 0; e < 8; ++e) s[e] += (float)p[e];
    }
    const int col = (g * 8) & (HID - 1);
    const float4 b0 = *(const float4*)(bias + col);
    const float4 b1 = *(const float4*)(bias + col + 4);
    f16x8 o;
    o[0] = (_Float16)fmaxf(s[0] + b0.x, 0.0f);
    o[1] = (_Float16)fmaxf(s[1] + b0.y, 0.0f);
    o[2] = (_Float16)fmaxf(s[2] + b0.z, 0.0f);
    o[3] = (_Float16)fmaxf(s[3] + b0.w, 0.0f);
    o[4] = (_Float16)fmaxf(s[4] + b1.x, 0.0f);
    o[5] = (_Float16)fmaxf(s[5] + b1.y, 0.0f);
    o[6] = (_Float16)fmaxf(s[6] + b1.z, 0.0f);
    o[7] = (_Float16)fmaxf(s[7] + b1.w, 0.0f);
    ((f16x8*)H)[g] = o;
}

// ---------------------------------------------------------------------------
// relu(sum_z P[z] + bias) -> f32  (H must NOT alias P)
// ---------------------------------------------------------------------------
__global__ __launch_bounds__(256) void combine_relu_f32(
    const _Float16* __restrict__ P, int Z, const float* __restrict__ bias,
    float* __restrict__ H)
{
    const int g = blockIdx.x * 256 + threadIdx.x;      // f16x8 group
    const size_t MN8 = (size_t)NROI * HID / 8;
    float s[8] = {0, 0, 0, 0, 0, 0, 0, 0};
    for (int z = 0; z < Z; ++z) {
        const f16x8 p = ((const f16x8*)P)[z * MN8 + g];
#pragma unroll
        for (int e = 0; e < 8; ++e) s[e] += (float)p[e];
    }
    const int col = (g * 8) & (HID - 1);
    const float4 b0 = *(const float4*)(bias + col);
    const float4 b1 = *(const float4*)(bias + col + 4);
    float4 r0, r1;
    r0.x = fmaxf(s[0] + b0.x, 0.0f);
    r0.y = fmaxf(s[1] + b0.y, 0.0f);
    r0.z = fmaxf(s[2] + b0.z, 0.0f);
    r0.w = fmaxf(s[3] + b0.w, 0.0f);
    r1.x = fmaxf(s[4] + b1.x, 0.0f);
    r1.y = fmaxf(s[5] + b1.y, 0.0f);
    r1.z = fmaxf(s[6] + b1.z, 0.0f);
    r1.w = fmaxf(s[7] + b1.w, 0.0f);
    ((float4*)H)[g * 2]     = r0;
    ((float4*)H)[g * 2 + 1] = r1;
}

// ---------------------------------------------------------------------------
// heads: one wave per ROI row; 10 dots of K=1024, shfl_xor reduce.
// ---------------------------------------------------------------------------
__global__ __launch_bounds__(256) void heads_kernel(
    const float* __restrict__ h2,
    const float* __restrict__ wc, const float* __restrict__ bc,
    const float* __restrict__ wb, const float* __restrict__ bb,
    float* __restrict__ out)
{
    const int gw   = (blockIdx.x * 256 + threadIdx.x) >> 6;
    const int lane = threadIdx.x & 63;
    const float* hrow = h2 + (size_t)gw * HID;

    float4 h[4];
#pragma unroll
    for (int j = 0; j < 4; ++j)
        h[j] = *(const float4*)(hrow + lane * 16 + j * 4);

    float keep = 0.0f;
#pragma unroll
    for (int o = 0; o < 10; ++o) {
        const float* wrow = (o < 2) ? (wc + (size_t)o * HID)
                                    : (wb + (size_t)(o - 2) * HID);
        float acc = 0.0f;
#pragma unroll
        for (int j = 0; j < 4; ++j) {
            const float4 w4 = *(const float4*)(wrow + lane * 16 + j * 4);
            acc += h[j].x * w4.x + h[j].y * w4.y + h[j].z * w4.z + h[j].w * w4.w;
        }
#pragma unroll
        for (int s = 32; s; s >>= 1) acc += __shfl_xor(acc, s, 64);
        if (lane == o) keep = acc;
    }
    if (lane < 2)        out[gw * 2 + lane] = keep + bc[lane];
    else if (lane < 10)  out[NROI * 2 + gw * 8 + (lane - 2)] = keep + bb[lane - 2];
}

// ---------------------------------------------------------------------------
extern "C" void kernel_launch(void* const* d_in, const int* in_sizes, int n_in,
                              void* d_out, int out_size, void* d_ws, size_t ws_size,
                              hipStream_t stream)
{
    const float* x    = (const float*)d_in[0];
    const float* rois = (const float*)d_in[1];
    const float* w1   = (const float*)d_in[2];
    const float* b1   = (const float*)d_in[3];
    const float* w2   = (const float*)d_in[4];
    const float* b2   = (const float*)d_in[5];
    const float* wc   = (const float*)d_in[6];
    const float* bc   = (const float*)d_in[7];
    const float* wb   = (const float*)d_in[8];
    const float* bb   = (const float*)d_in[9];
    float* out = (float*)d_out;

    char* ws = (char*)d_ws;
    const size_t W1B = (size_t)HID * FANIN * 2;        // 25,690,112
    const size_t W2B = (size_t)HID * HID * 2;          //  2,097,152
    const size_t CRB = (size_t)NROI * FANIN * 2;       // 51,380,224
    const size_t PB  = (size_t)NROI * HID * 2;         //  4,194,304 per z (f16)
    const size_t HB  = (size_t)NROI * HID * 2;         //  4,194,304
    const size_t XTB = (size_t)4 * IMH * IMW * CCH * 2;// 81,920,000

    const int Z1 = 7;   // FC1 K-split: 12544/7 = 1792 = 28 x 64
    const int Z2 = 2;   // FC2 K-split: 1024/2  = 512 =  8 x 64

    size_t off = 0;
    _Float16* w1P    = (_Float16*)(ws + off); off += W1B;
    _Float16* w2F    = (_Float16*)(ws + off); off += W2B;
    _Float16* cropsP = (_Float16*)(ws + off); off += CRB;
    _Float16* P      = (_Float16*)(ws + off); off += (size_t)Z1 * PB;
    _Float16* h1F    = (_Float16*)(ws + off); off += HB;
    _Float16* xT     = (_Float16*)(ws + off); off += XTB;   // total ~194.6 MB
    // x16 (82 MB) aliases crops+P+h1F (84.9 MB) -- all dead until gather/FC1
    _Float16* x16    = cropsP;
    float*    h2     = (float*)xT;   // xT dead after gather; h2 needs 8.4 MB

    // Pass A: convert x -> x16 (sequential) + permute w1 + convert w2
    prep_convert<<<3136, 256, 0, stream>>>(x, x16, w1, w1P, w2, w2F);

    // Pass B: transpose x16 -> xT (reads L3-resident x16)
    transpose16<<<dim3(2, IMH, 4), 256, 0, stream>>>(x16, xT);

    // RoIAlign gather: block per ROI, wave per sample (overwrites x16 - dead)
    roi_gather_kernel<<<NROI, 256, 0, stream>>>(xT, rois, cropsP);

    // FC1: 256x256 dbuf tile, XCD-pinned flat grid (224 blocks), f16 partials
    gemm_f16_256<<<224, 512, 0, stream>>>(
        cropsP, w1P, P, NROI, HID, FANIN, FANIN / Z1);
    combine_relu_f16<<<(NROI * HID / 8) / 256, 256, 0, stream>>>(P, Z1, b1, h1F);

    // FC2: K = 1024, 128x128 dbuf tile, Z=2
    gemm_f16<<<dim3(HID / 128, NROI / 128, Z2), 256, 0, stream>>>(
        h1F, w2F, P, NROI, HID, HID, HID / Z2);
    combine_relu_f32<<<(NROI * HID / 8) / 256, 256, 0, stream>>>(P, Z2, b2, h2);

    // heads
    heads_kernel<<<NROI / 4, 256, 0, stream>>>(h2, wc, bc, wb, bb, out);
}

// Round 25
// 186.704 us; speedup vs baseline: 1.1751x; 1.1751x over previous
//
#include <hip/hip_runtime.h>

#define NROI  2048
#define CCH   256
#define IMH   200
#define IMW   200
#define CROP  7
#define PP    49
#define FANIN 12544
#define HID   1024

typedef _Float16 f16x8 __attribute__((ext_vector_type(8)));
typedef _Float16 f16x4 __attribute__((ext_vector_type(4)));
typedef __attribute__((ext_vector_type(4))) float f32x4;

__device__ __forceinline__ void gload16(const void* g, void* l) {
    __builtin_amdgcn_global_load_lds(
        (const __attribute__((address_space(1))) void*)g,
        (__attribute__((address_space(3))) void*)l, 16, 0, 0);
}

// ---------------------------------------------------------------------------
// Fused prep. Blocks [0,3200): transpose tile (b,h,cquad): 64 channel rows
// DMA-staged to LDS at PADDED stride 201 floats (row c -> smem + c*804), so
// the write-phase column reads are 2-way max. [3200,4224): permute w1;
// [4224,4288): convert w2. 51.5 KB -> 3 blocks/CU.
// NOTE: this phase is pinned at the measured ~2.3 TB/s x-read ceiling; six
// access-pattern variants (16B..800B runs, DMA, copy) all land at 103-112us.
// ---------------------------------------------------------------------------
__global__ __launch_bounds__(256) void prep_all(
    const float* __restrict__ x, _Float16* __restrict__ xT,
    const float* __restrict__ w1, _Float16* __restrict__ w1P,
    const float* __restrict__ w2, _Float16* __restrict__ w2F)
{
    __shared__ char smem[51456];
    const int bid = blockIdx.x;
    const int tid = threadIdx.x;

    if (bid < 3200) {
        // ---- transpose x[b][c0..c0+63][h][:] f32 -> xT[b][h][:][c0..c0+63] ----
        float* buf = (float*)smem;          // [64][201] padded
        const int b  = bid / 800;
        const int r  = bid - b * 800;
        const int h  = r >> 2;
        const int cq = r & 3;
        const int c0 = cq * 64;
        const int wave = tid >> 6, lane = tid & 63;

        const float* chb = x + ((size_t)(b * CCH + c0) * IMH + h) * IMW;
        // stage: one 800-B chunk per channel row; lanes 0..49 active;
        // dest = smem + c*804 (HW adds lane*16) -> padded row stride 201 f32
        if (lane < 50) {
            const int cEnd = wave * 16 + 16;
            for (int c = wave * 16; c < cEnd; ++c)
                gload16(chb + (size_t)c * (IMH * IMW) + lane * 4,
                        smem + c * 804);
        }
        __syncthreads();   // vmcnt(0) drain -> buf ready

        // write: unit u = (w, seg); banks (8sg+9k+w)%32 -> 2-way max
        _Float16* dst0 = xT + ((size_t)(b * IMH + h) * IMW) * CCH + c0;
        for (int u = tid; u < 1600; u += 256) {
            const int w  = u >> 3;
            const int sg = u & 7;
            f16x8 o;
#pragma unroll
            for (int k = 0; k < 8; ++k)
                o[k] = (_Float16)buf[(sg * 8 + k) * 201 + w];
            *(f16x8*)(dst0 + (size_t)w * CCH + sg * 8) = o;
        }
    } else if (bid < 4224) {
        // ---- permute w1: w1P[o][p*256+c] = (f16) w1[o][c*49+p] ----
        _Float16* row = (_Float16*)smem;
        const int o = bid - 3200;
        const float* src = w1 + (size_t)o * FANIN;

        for (int g = tid; g < FANIN / 4; g += 256) {
            const float4 v = *(const float4*)(src + g * 4);
            f16x4 f = {(_Float16)v.x, (_Float16)v.y, (_Float16)v.z, (_Float16)v.w};
            *(f16x4*)&row[g * 4] = f;
        }
        __syncthreads();

        _Float16* dst = w1P + (size_t)o * FANIN;
        for (int g = tid; g < FANIN; g += 256) {
            const int p = g >> 8;          // 0..48
            const int c = g & 255;
            dst[g] = row[c * PP + p];
        }
    } else {
        // ---- convert w2 f32 -> f16 ----
        const int cb = bid - 4224;         // 0..63
        for (int g = cb * 256 + tid; g < HID * HID / 4; g += 64 * 256) {
            const float4 v = ((const float4*)w2)[g];
            f16x4 o = {(_Float16)v.x, (_Float16)v.y, (_Float16)v.z, (_Float16)v.w};
            ((f16x4*)w2F)[g] = o;
        }
    }
}

// ---------------------------------------------------------------------------
// RoIAlign gather: block = ROI n, 4 waves; wave = one sample across channels.
// Crops K-order: k' = p*256 + c  (w1 permuted identically).
// ---------------------------------------------------------------------------
__global__ __launch_bounds__(256) void roi_gather_kernel(
    const _Float16* __restrict__ xT, const float* __restrict__ rois,
    _Float16* __restrict__ crops)
{
    const int n    = blockIdx.x;
    const int wave = threadIdx.x >> 6;
    const int lane = threadIdx.x & 63;

    const int   b   = (int)rois[(size_t)n * 5 + 0];
    const float rx1 = rois[(size_t)n * 5 + 1];
    const float ry1 = rois[(size_t)n * 5 + 2];
    const float rx2 = rois[(size_t)n * 5 + 3];
    const float ry2 = rois[(size_t)n * 5 + 4];
    const float bw = (rx2 - rx1) / 7.0f;
    const float bh = (ry2 - ry1) / 7.0f;

    const _Float16* xb = xT + (size_t)b * (IMH * IMW * CCH);
    _Float16* crow = crops + (size_t)n * FANIN;

    for (int p = wave; p < PP; p += 4) {
        const int i = p / 7;           // bin row -> y
        const int j = p - i * 7;       // bin col -> x
        float px = __fadd_rn(rx1, __fmul_rn((float)j + 0.5f, bw));
        float py = __fadd_rn(ry1, __fmul_rn((float)i + 0.5f, bh));
        px = fminf(fmaxf(px, 0.0f), (float)(IMW - 1));
        py = fminf(fmaxf(py, 0.0f), (float)(IMH - 1));
        const float fx = floorf(px), fy = floorf(py);
        const int x0 = (int)fx, y0 = (int)fy;
        const int dxo = (min(x0 + 1, IMW - 1) - x0) * CCH;
        const int dyo = (min(y0 + 1, IMH - 1) - y0) * (IMW * CCH);
        const float wx = px - fx, wy = py - fy;

        const _Float16* cb = xb + (size_t)(y0 * IMW + x0) * CCH + lane * 4;
        const f16x4 A = *(const f16x4*)(cb);
        const f16x4 B = *(const f16x4*)(cb + dxo);
        const f16x4 C = *(const f16x4*)(cb + dyo);
        const f16x4 D = *(const f16x4*)(cb + dyo + dxo);

        f16x4 o;
#pragma unroll
        for (int e = 0; e < 4; ++e) {
            const float v00 = (float)A[e], v01 = (float)B[e];
            const float v10 = (float)C[e], v11 = (float)D[e];
            const float top = v00 + wx * (v01 - v00);
            const float bot = v10 + wx * (v11 - v10);
            o[e] = (_Float16)(top + wy * (bot - top));
        }
        *(f16x4*)(crow + p * CCH + lane * 4) = o;
    }
}

// ---------------------------------------------------------------------------
// FC1 GEMM (NT), 256x256 tile, BK=64, 8 waves, double-buffered 2-phase,
// XCD-pinned flat grid (224 blocks). P partials stored as f16.
// ---------------------------------------------------------------------------
__global__ __launch_bounds__(512, 1) void gemm_f16_256(
    const _Float16* __restrict__ A, const _Float16* __restrict__ B,
    _Float16* __restrict__ P, int M, int N, int K, int kLen)
{
    __shared__ _Float16 lds[2][2][256][64];   // [buf][op][row][slot] 128 KB

    const int flat = blockIdx.x;
    const int xcd  = flat & 7;
    const int idx  = flat >> 3;          // 0..27
    const int bn4  = xcd & 3;            // n-tile 0..3
    const int half = xcd >> 2;           // 0..1
    const int bm8  = half * 4 + (idx & 3);   // m-tile 0..7
    const int z    = idx >> 2;           // 0..6

    const int tid  = threadIdx.x;
    const int wave = tid >> 6;           // 0..7
    const int lane = tid & 63;
    const int bm = bm8 * 256;
    const int bn = bn4 * 256;
    const int kBase = z * kLen;
    const int wr = wave >> 1;            // 0..3 (M)
    const int wc = wave & 1;             // 0..1 (N)

    f32x4 acc[4][8];
#pragma unroll
    for (int i = 0; i < 4; ++i)
#pragma unroll
        for (int j = 0; j < 8; ++j) acc[i][j] = (f32x4){0.f, 0.f, 0.f, 0.f};

    const int r_st = wave * 32 + (lane >> 3);
    const int s_st = ((lane & 7) ^ ((lane >> 4) & 3)) * 8;   // f16 units
    const _Float16* gA = A + (size_t)(bm + r_st) * K + kBase + s_st;
    const _Float16* gB = B + (size_t)(bn + r_st) * K + kBase + s_st;
    const size_t rstep8 = (size_t)8 * K;

    const int li = lane & 15;
    const int hi = lane >> 4;            // 0..3
    const int swb = (li >> 1) & 3;       // row-pair xor term

    // prologue: stage tile 0 into buf 0
    {
        _Float16* dA = &lds[0][0][wave * 32][0];
        _Float16* dB = &lds[0][1][wave * 32][0];
#pragma unroll
        for (int ck = 0; ck < 4; ++ck) {
            gload16(gA + ck * rstep8, dA + ck * 512);
            gload16(gB + ck * rstep8, dB + ck * 512);
        }
    }
    __syncthreads();

    int cur = 0;
    for (int kt = 0; kt < kLen; kt += 64) {
        if (kt + 64 < kLen) {
            _Float16* dA = &lds[cur ^ 1][0][wave * 32][0];
            _Float16* dB = &lds[cur ^ 1][1][wave * 32][0];
#pragma unroll
            for (int ck = 0; ck < 4; ++ck) {
                gload16(gA + kt + 64 + ck * rstep8, dA + ck * 512);
                gload16(gB + kt + 64 + ck * rstep8, dB + ck * 512);
            }
        }

#pragma unroll
        for (int kk = 0; kk < 2; ++kk) {
            const int sw = (((kk << 2) | hi) ^ swb) * 8;     // f16 offset
            f16x8 a[4], b[8];
#pragma unroll
            for (int m = 0; m < 4; ++m)
                a[m] = *(const f16x8*)&lds[cur][0][wr * 64 + m * 16 + li][sw];
#pragma unroll
            for (int n = 0; n < 8; ++n)
                b[n] = *(const f16x8*)&lds[cur][1][wc * 128 + n * 16 + li][sw];
#pragma unroll
            for (int m = 0; m < 4; ++m)
#pragma unroll
                for (int n = 0; n < 8; ++n)
                    acc[m][n] = __builtin_amdgcn_mfma_f32_16x16x32_f16(a[m], b[n], acc[m][n], 0, 0, 0);
        }
        __syncthreads();
        cur ^= 1;
    }

    _Float16* Pz = P + (size_t)z * M * N;
#pragma unroll
    for (int m = 0; m < 4; ++m)
#pragma unroll
        for (int n = 0; n < 8; ++n) {
            const int col = bn + wc * 128 + n * 16 + li;
#pragma unroll
            for (int e = 0; e < 4; ++e) {
                const int row = bm + wr * 64 + m * 16 + hi * 4 + e;
                Pz[(size_t)row * N + col] = (_Float16)acc[m][n][e];
            }
        }
}

// ---------------------------------------------------------------------------
// FC2 GEMM (NT), 128x128 tile, BK=64, double-buffered 2-phase, f16 partials.
// ---------------------------------------------------------------------------
__global__ __launch_bounds__(256, 2) void gemm_f16(
    const _Float16* __restrict__ A, const _Float16* __restrict__ B,
    _Float16* __restrict__ P, int M, int N, int K, int kLen)
{
    __shared__ _Float16 lds[2][2][128][64];   // 64 KB -> 2 blocks/CU

    const int tid  = threadIdx.x;
    const int wave = tid >> 6;
    const int lane = tid & 63;
    const int bm = blockIdx.y * 128;
    const int bn = blockIdx.x * 128;
    const int kBase = blockIdx.z * kLen;
    const int wr = wave >> 1, wc = wave & 1;

    f32x4 acc[4][4];
#pragma unroll
    for (int i = 0; i < 4; ++i)
#pragma unroll
        for (int j = 0; j < 4; ++j) acc[i][j] = (f32x4){0.f, 0.f, 0.f, 0.f};

    const int r_st = wave * 32 + (lane >> 3);
    const int s_st = ((lane & 7) ^ ((lane >> 4) & 3)) * 8;   // f16 units
    const _Float16* gA = A + (size_t)(bm + r_st) * K + kBase + s_st;
    const _Float16* gB = B + (size_t)(bn + r_st) * K + kBase + s_st;
    const size_t rstep8 = (size_t)8 * K;

    const int li = lane & 15;
    const int hi = lane >> 4;            // 0..3
    const int swb = (li >> 1) & 3;       // row-pair xor term

    {
        _Float16* dA = &lds[0][0][wave * 32][0];
        _Float16* dB = &lds[0][1][wave * 32][0];
#pragma unroll
        for (int ck = 0; ck < 4; ++ck) {
            gload16(gA + ck * rstep8, dA + ck * 512);
            gload16(gB + ck * rstep8, dB + ck * 512);
        }
    }
    __syncthreads();

    int cur = 0;
    for (int kt = 0; kt < kLen; kt += 64) {
        if (kt + 64 < kLen) {
            _Float16* dA = &lds[cur ^ 1][0][wave * 32][0];
            _Float16* dB = &lds[cur ^ 1][1][wave * 32][0];
#pragma unroll
            for (int ck = 0; ck < 4; ++ck) {
                gload16(gA + kt + 64 + ck * rstep8, dA + ck * 512);
                gload16(gB + kt + 64 + ck * rstep8, dB + ck * 512);
            }
        }

#pragma unroll
        for (int kk = 0; kk < 2; ++kk) {
            const int sw = (((kk << 2) | hi) ^ swb) * 8;     // f16 offset
            f16x8 a[4], b[4];
#pragma unroll
            for (int m = 0; m < 4; ++m)
                a[m] = *(const f16x8*)&lds[cur][0][wr * 64 + m * 16 + li][sw];
#pragma unroll
            for (int n = 0; n < 4; ++n)
                b[n] = *(const f16x8*)&lds[cur][1][wc * 64 + n * 16 + li][sw];
#pragma unroll
            for (int m = 0; m < 4; ++m)
#pragma unroll
                for (int n = 0; n < 4; ++n)
                    acc[m][n] = __builtin_amdgcn_mfma_f32_16x16x32_f16(a[m], b[n], acc[m][n], 0, 0, 0);
        }
        __syncthreads();
        cur ^= 1;
    }

    _Float16* Pz = P + (size_t)blockIdx.z * M * N;
#pragma unroll
    for (int m = 0; m < 4; ++m)
#pragma unroll
        for (int n = 0; n < 4; ++n) {
            const int col = bn + wc * 64 + n * 16 + li;
#pragma unroll
            for (int e = 0; e < 4; ++e) {
                const int row = bm + wr * 64 + m * 16 + hi * 4 + e;
                Pz[(size_t)row * N + col] = (_Float16)acc[m][n][e];
            }
        }
}

// ---------------------------------------------------------------------------
// relu(sum_z P[z] + bias) -> f16   (P slices are f16; accumulate in f32)
// ---------------------------------------------------------------------------
__global__ __launch_bounds__(256) void combine_relu_f16(
    const _Float16* __restrict__ P, int Z, const float* __restrict__ bias,
    _Float16* __restrict__ H)
{
    const int g = blockIdx.x * 256 + threadIdx.x;      // f16x8 group
    const size_t MN8 = (size_t)NROI * HID / 8;
    float s[8] = {0, 0, 0, 0, 0, 0, 0, 0};
    for (int z = 0; z < Z; ++z) {
        const f16x8 p = ((const f16x8*)P)[z * MN8 + g];
#pragma unroll
        for (int e = 0; e < 8; ++e) s[e] += (float)p[e];
    }
    const int col = (g * 8) & (HID - 1);
    const float4 b0 = *(const float4*)(bias + col);
    const float4 b1 = *(const float4*)(bias + col + 4);
    f16x8 o;
    o[0] = (_Float16)fmaxf(s[0] + b0.x, 0.0f);
    o[1] = (_Float16)fmaxf(s[1] + b0.y, 0.0f);
    o[2] = (_Float16)fmaxf(s[2] + b0.z, 0.0f);
    o[3] = (_Float16)fmaxf(s[3] + b0.w, 0.0f);
    o[4] = (_Float16)fmaxf(s[4] + b1.x, 0.0f);
    o[5] = (_Float16)fmaxf(s[5] + b1.y, 0.0f);
    o[6] = (_Float16)fmaxf(s[6] + b1.z, 0.0f);
    o[7] = (_Float16)fmaxf(s[7] + b1.w, 0.0f);
    ((f16x8*)H)[g] = o;
}

// ---------------------------------------------------------------------------
// relu(sum_z P[z] + bias) -> f32  (H must NOT alias P)
// ---------------------------------------------------------------------------
__global__ __launch_bounds__(256) void combine_relu_f32(
    const _Float16* __restrict__ P, int Z, const float* __restrict__ bias,
    float* __restrict__ H)
{
    const int g = blockIdx.x * 256 + threadIdx.x;      // f16x8 group
    const size_t MN8 = (size_t)NROI * HID / 8;
    float s[8] = {0, 0, 0, 0, 0, 0, 0, 0};
    for (int z = 0; z < Z; ++z) {
        const f16x8 p = ((const f16x8*)P)[z * MN8 + g];
#pragma unroll
        for (int e = 0; e < 8; ++e) s[e] += (float)p[e];
    }
    const int col = (g * 8) & (HID - 1);
    const float4 b0 = *(const float4*)(bias + col);
    const float4 b1 = *(const float4*)(bias + col + 4);
    float4 r0, r1;
    r0.x = fmaxf(s[0] + b0.x, 0.0f);
    r0.y = fmaxf(s[1] + b0.y, 0.0f);
    r0.z = fmaxf(s[2] + b0.z, 0.0f);
    r0.w = fmaxf(s[3] + b0.w, 0.0f);
    r1.x = fmaxf(s[4] + b1.x, 0.0f);
    r1.y = fmaxf(s[5] + b1.y, 0.0f);
    r1.z = fmaxf(s[6] + b1.z, 0.0f);
    r1.w = fmaxf(s[7] + b1.w, 0.0f);
    ((float4*)H)[g * 2]     = r0;
    ((float4*)H)[g * 2 + 1] = r1;
}

// ---------------------------------------------------------------------------
// heads: one wave per ROI row; 10 dots of K=1024, shfl_xor reduce.
// ---------------------------------------------------------------------------
__global__ __launch_bounds__(256) void heads_kernel(
    const float* __restrict__ h2,
    const float* __restrict__ wc, const float* __restrict__ bc,
    const float* __restrict__ wb, const float* __restrict__ bb,
    float* __restrict__ out)
{
    const int gw   = (blockIdx.x * 256 + threadIdx.x) >> 6;
    const int lane = threadIdx.x & 63;
    const float* hrow = h2 + (size_t)gw * HID;

    float4 h[4];
#pragma unroll
    for (int j = 0; j < 4; ++j)
        h[j] = *(const float4*)(hrow + lane * 16 + j * 4);

    float keep = 0.0f;
#pragma unroll
    for (int o = 0; o < 10; ++o) {
        const float* wrow = (o < 2) ? (wc + (size_t)o * HID)
                                    : (wb + (size_t)(o - 2) * HID);
        float acc = 0.0f;
#pragma unroll
        for (int j = 0; j < 4; ++j) {
            const float4 w4 = *(const float4*)(wrow + lane * 16 + j * 4);
            acc += h[j].x * w4.x + h[j].y * w4.y + h[j].z * w4.z + h[j].w * w4.w;
        }
#pragma unroll
        for (int s = 32; s; s >>= 1) acc += __shfl_xor(acc, s, 64);
        if (lane == o) keep = acc;
    }
    if (lane < 2)        out[gw * 2 + lane] = keep + bc[lane];
    else if (lane < 10)  out[NROI * 2 + gw * 8 + (lane - 2)] = keep + bb[lane - 2];
}

// ---------------------------------------------------------------------------
extern "C" void kernel_launch(void* const* d_in, const int* in_sizes, int n_in,
                              void* d_out, int out_size, void* d_ws, size_t ws_size,
                              hipStream_t stream)
{
    const float* x    = (const float*)d_in[0];
    const float* rois = (const float*)d_in[1];
    const float* w1   = (const float*)d_in[2];
    const float* b1   = (const float*)d_in[3];
    const float* w2   = (const float*)d_in[4];
    const float* b2   = (const float*)d_in[5];
    const float* wc   = (const float*)d_in[6];
    const float* bc   = (const float*)d_in[7];
    const float* wb   = (const float*)d_in[8];
    const float* bb   = (const float*)d_in[9];
    float* out = (float*)d_out;

    char* ws = (char*)d_ws;
    const size_t CRB = (size_t)NROI * FANIN * 2;       // 51,380,224
    const size_t W1B = (size_t)HID * FANIN * 2;        // 25,690,112
    const size_t W2B = (size_t)HID * HID * 2;          //  2,097,152
    const size_t PB  = (size_t)NROI * HID * 2;         //  4,194,304 per z (f16)
    const size_t HB  = (size_t)NROI * HID * 2;         //  4,194,304
    const size_t XTB = (size_t)4 * IMH * IMW * CCH * 2;// 81,920,000

    const int Z1 = 7;   // FC1 K-split: 12544/7 = 1792 = 28 x 64
    const int Z2 = 2;   // FC2 K-split: 1024/2  = 512 =  8 x 64

    size_t off = 0;
    _Float16* cropsP = (_Float16*)(ws + off); off += CRB;
    _Float16* w1P    = (_Float16*)(ws + off); off += W1B;
    _Float16* w2F    = (_Float16*)(ws + off); off += W2B;
    _Float16* P      = (_Float16*)(ws + off); off += (size_t)Z1 * PB;
    _Float16* h1F    = (_Float16*)(ws + off); off += HB;
    _Float16* xT     = (_Float16*)(ws + off); off += XTB;   // total ~195 MB
    float*    h2     = (float*)xT;   // xT dead after gather; h2 needs 8.4 MB

    // fused prep: padded-stride DMA transpose + permute w1 + convert w2
    prep_all<<<4288, 256, 0, stream>>>(x, xT, w1, w1P, w2, w2F);

    // RoIAlign gather: block per ROI, wave per sample
    roi_gather_kernel<<<NROI, 256, 0, stream>>>(xT, rois, cropsP);

    // FC1: 256x256 dbuf tile, XCD-pinned flat grid (224 blocks), f16 partials
    gemm_f16_256<<<224, 512, 0, stream>>>(
        cropsP, w1P, P, NROI, HID, FANIN, FANIN / Z1);
    combine_relu_f16<<<(NROI * HID / 8) / 256, 256, 0, stream>>>(P, Z1, b1, h1F);

    // FC2: K = 1024, 128x128 dbuf tile, Z=2
    gemm_f16<<<dim3(HID / 128, NROI / 128, Z2), 256, 0, stream>>>(
        h1F, w2F, P, NROI, HID, HID, HID / Z2);
    combine_relu_f32<<<(NROI * HID / 8) / 256, 256, 0, stream>>>(P, Z2, b2, h2);

    // heads
    heads_kernel<<<NROI / 4, 256, 0, stream>>>(h2, wc, bc, wb, bb, out);
}